// Round 11
// baseline (149.614 us; speedup 1.0000x reference)
//
#include <hip/hip_runtime.h>
#include <math.h>
#include <stdint.h>

typedef unsigned long long u64;

#define HH 1024
#define WW 1024
#define NB 8
#define WPR 16  // u64 words per image row (1024/64)

// LDS layout (single block, manual offsets):
//   sInF  [70][72] floats  @ 0       (20160 B)  rows 16B-aligned; cols 70..71 pad
//   sBlF  [68][68] floats  @ 20160   (18496 B)
//   sBkt  [66][68] chars   @ 38656   ( 4488 B)
//   sMagF [66][68] floats  = reuse of sInF region after blur
#define SMEM_BYTES 43152

// Exact bucket: bit-identical to the validated reference chain (R9/R10 pass).
__device__ __forceinline__ int bucket_exact(float sy, float sx) {
#pragma clang fp contract(off)
    float ang = (float)atan2((double)sy, (double)sx);
    float deg = ang * 57.29577951308232f;  // f32(180/pi)
    if (deg < 0.f) deg += 180.f;
    if (deg < 22.5f || deg >= 157.5f) return 0;
    if (deg < 67.5f) return 1;
    if (deg < 112.5f) return 2;
    return 3;
}

// Guarded bucket (validated in R10): cheap tan-ratio away from boundaries,
// bit-exact atan2 chain within the guard band.
__device__ __forceinline__ int bucket_of(float sy, float sx) {
#pragma clang fp contract(off)
    const float t1 = 0.41421356237309503f;  // tan 22.5
    const float t2 = 2.414213562373095f;    // tan 67.5
    float ax = fabsf(sx), ay = fabsf(sy);
    float r1 = t1 * ax, r2 = t2 * ax;
    bool near1 = fabsf(ay - r1) <= 1e-4f * (ay + r1);
    bool near2 = fabsf(ay - r2) <= 1e-4f * (ay + r2);
    if (near1 | near2) return bucket_exact(sy, sx);
    if (ay < r1) return 0;
    if (ay < r2) return ((sx > 0.f) == (sy > 0.f)) ? 1 : 3;
    return 2;
}

// ---------------- Kernel 1: blur + sobel + NMS + double threshold -> bitmaps ----------------
__global__ __launch_bounds__(256) void canny_s1(const float* __restrict__ in,
                                                u64* __restrict__ strongB,
                                                u64* __restrict__ weakB) {
#pragma clang fp contract(off)
    const int bx  = blockIdx.x;
    const int b   = bx >> 8;
    const int rem = bx & 255;
    const int y0  = (rem >> 4) << 6;
    const int x0  = (rem & 15) << 6;
    const float* img = in + (size_t)b * (HH * WW);

    __shared__ __align__(16) char smem[SMEM_BYTES];
    float* sInF = (float*)smem;                       // [70][72]
    float* sBlF = (float*)(smem + 20160);             // [68][68]
    unsigned char* sBkt = (unsigned char*)(smem + 38656);  // [66][68]
    float* sMagF = sInF;                              // [66][68] reuse

    const int tid = threadIdx.x;

    // ---- Phase 0: load input tile (stride 72), zero outside image ----
    for (int idx = tid; idx < 70 * 70; idx += 256) {
        int r = idx / 70, c = idx - r * 70;
        int gy = y0 - 3 + r, gx = x0 - 3 + c;
        float v = 0.f;
        if ((unsigned)gy < HH && (unsigned)gx < WW) v = img[gy * WW + gx];
        sInF[r * 72 + c] = v;
    }
    __syncthreads();

    // ---- Phase 1: Gaussian blur, 4 px/thread, b128 LDS reads ----
    // 68 rows x 17 quads; output (r,c) at global (y0-2+r, x0-2+c).
    for (int q = tid; q < 68 * 17; q += 256) {
        int r = q / 17, c4 = (q - r * 17) * 4;
        // window cols c4..c4+7 of rows r..r+2 (outputs use cols c4..c4+5)
        const float4* p0 = (const float4*)&sInF[r * 72 + c4];
        const float4* p1 = (const float4*)&sInF[(r + 1) * 72 + c4];
        const float4* p2 = (const float4*)&sInF[(r + 2) * 72 + c4];
        float4 a0 = p0[0], b0 = p0[1];
        float4 a1 = p1[0], b1 = p1[1];
        float4 a2 = p2[0], b2 = p2[1];
        float w0[6] = {a0.x, a0.y, a0.z, a0.w, b0.x, b0.y};
        float w1[6] = {a1.x, a1.y, a1.z, a1.w, b1.x, b1.y};
        float w2[6] = {a2.x, a2.y, a2.z, a2.w, b2.x, b2.y};
        int gy = y0 - 2 + r;
        float4 outv;
        float res[4];
#pragma unroll
        for (int j = 0; j < 4; ++j) {
            // exact reference row-major order per pixel
            float s = w0[j] * 0.0625f;
            s += w0[j + 1] * 0.125f;
            s += w0[j + 2] * 0.0625f;
            s += w1[j] * 0.125f;
            s += w1[j + 1] * 0.25f;
            s += w1[j + 2] * 0.125f;
            s += w2[j] * 0.0625f;
            s += w2[j + 1] * 0.125f;
            s += w2[j + 2] * 0.0625f;
            int gx = x0 - 2 + c4 + j;
            res[j] = ((unsigned)gy < HH && (unsigned)gx < WW) ? s : 0.f;
        }
        outv.x = res[0]; outv.y = res[1]; outv.z = res[2]; outv.w = res[3];
        *(float4*)&sBlF[r * 68 + c4] = outv;
    }
    __syncthreads();

    // ---- Phase 2: sobel + mag + bucket, 4 px/thread ----
    // 66 rows x 17 quads; output (r,c) at global (y0-1+r, x0-1+c).
    // Quad c4=64 computes pad cols 66,67 from garbage (in-LDS reads; outputs
    // land in pad cols never read downstream).
    for (int q = tid; q < 66 * 17; q += 256) {
        int r = q / 17, c4 = (q - r * 17) * 4;
        const float4* p0 = (const float4*)&sBlF[r * 68 + c4];
        const float4* p1 = (const float4*)&sBlF[(r + 1) * 68 + c4];
        const float4* p2 = (const float4*)&sBlF[(r + 2) * 68 + c4];
        float4 a0 = p0[0], b0 = p0[1];
        float4 a1 = p1[0], b1 = p1[1];
        float4 a2 = p2[0], b2 = p2[1];
        float w0[6] = {a0.x, a0.y, a0.z, a0.w, b0.x, b0.y};
        float w1[6] = {a1.x, a1.y, a1.z, a1.w, b1.x, b1.y};
        float w2[6] = {a2.x, a2.y, a2.z, a2.w, b2.x, b2.y};
        int gy = y0 - 1 + r;
        float res[4];
        unsigned bpack = 0;
#pragma unroll
        for (int j = 0; j < 4; ++j) {
            // exact reference row-major signed order per pixel
            float gxv = -w0[j];
            gxv += w0[j + 2];
            gxv -= 2.f * w1[j];
            gxv += 2.f * w1[j + 2];
            gxv -= w2[j];
            gxv += w2[j + 2];
            float gyv = -w0[j];
            gyv -= 2.f * w0[j + 1];
            gyv -= w0[j + 2];
            gyv += w2[j];
            gyv += 2.f * w2[j + 1];
            gyv += w2[j + 2];
            float xx = gxv * gxv;
            float yy = gyv * gyv;
            float v = sqrtf(xx + yy);
            int gx = x0 - 1 + c4 + j;
            bool inb = ((unsigned)gy < HH && (unsigned)gx < WW);
            res[j] = inb ? v : 0.f;
            int bk = bucket_of(gyv, gxv);
            bpack |= (unsigned)bk << (8 * j);
        }
        float4 outv;
        outv.x = res[0]; outv.y = res[1]; outv.z = res[2]; outv.w = res[3];
        *(float4*)&sMagF[r * 68 + c4] = outv;
        *(unsigned*)&sBkt[r * 68 + c4] = bpack;
    }
    __syncthreads();

    // ---- Phase 3: NMS + threshold, column-per-lane, 4 rows/step ----
    const int lane = tid & 63;
    const int wv   = tid >> 6;
    const int x    = lane;  // tile col

#pragma unroll
    for (int s = 0; s < 4; ++s) {
        int ys = wv * 16 + s * 4;  // mag-row base; outputs rows ys..ys+3
        float mm[6][3];
#pragma unroll
        for (int rr = 0; rr < 6; ++rr)
#pragma unroll
            for (int cc = 0; cc < 3; ++cc)
                mm[rr][cc] = sMagF[(ys + rr) * 68 + (x + cc)];

        bool st[4], wk[4];
#pragma unroll
        for (int j = 0; j < 4; ++j) {
            int bk = sBkt[(ys + 1 + j) * 68 + (x + 1)];
            float m = mm[j + 1][1];
            float n1, n2;
            if (bk == 0)      { n1 = mm[j + 1][2]; n2 = mm[j + 1][0]; }
            else if (bk == 1) { n1 = mm[j][2];     n2 = mm[j + 2][0]; }
            else if (bk == 2) { n1 = mm[j][1];     n2 = mm[j + 2][1]; }
            else              { n1 = mm[j][0];     n2 = mm[j + 2][2]; }
            bool keep = (m >= n1) && (m >= n2);
            st[j] = keep && (m >= 0.3f);
            wk[j] = keep && (m >= 0.1f) && (m < 0.3f);
        }

        u64 bs0 = __ballot(st[0]), bs1 = __ballot(st[1]);
        u64 bs2 = __ballot(st[2]), bs3 = __ballot(st[3]);
        u64 bw0 = __ballot(wk[0]), bw1 = __ballot(wk[1]);
        u64 bw2 = __ballot(wk[2]), bw3 = __ballot(wk[3]);
        if (lane == 0) {
            size_t o = (size_t)(b * HH + y0 + ys) * WPR + (x0 >> 6);
            strongB[o]           = bs0;
            strongB[o + WPR]     = bs1;
            strongB[o + 2 * WPR] = bs2;
            strongB[o + 3 * WPR] = bs3;
            weakB[o]             = bw0;
            weakB[o + WPR]       = bw1;
            weakB[o + 2 * WPR]   = bw2;
            weakB[o + 3 * WPR]   = bw3;
        }
    }
}

// ---------------- Kernel 2: register+shfl bit-parallel hysteresis ----------------
// One wave per 64x64 tile; lane L holds region rows 2L,2L+1 (96 rows in 48
// lanes) x 3 u64 words in registers. Wave-synchronous Jacobi, no LDS.
__global__ __launch_bounds__(256) void canny_s2(const u64* __restrict__ strongB,
                                                const u64* __restrict__ weakB,
                                                float* __restrict__ out) {
    const int wave = threadIdx.x >> 6;
    const int lane = threadIdx.x & 63;
    const int tile = blockIdx.x * 4 + wave;  // 0..2047
    const int b   = tile >> 8;
    const int rem = tile & 255;
    const int y0  = (rem >> 4) << 6;
    const int x0  = (rem & 15) << 6;
    const int w0  = (x0 >> 6) - 1;

    u64 e[2][3], k[2][3];
#pragma unroll
    for (int i = 0; i < 2; ++i) {
        int rr = 2 * lane + i;
        int gy = y0 - 16 + rr;
#pragma unroll
        for (int w = 0; w < 3; ++w) {
            int gw = w0 + w;
            u64 s = 0, kk = 0;
            if (rr < 96 && (unsigned)gy < HH && (unsigned)gw < WPR) {
                size_t o = (size_t)(b * HH + gy) * WPR + gw;
                s  = strongB[o];
                kk = weakB[o];
            }
            e[i][w] = s;
            k[i][w] = kk;
        }
    }

    for (int it = 0; it < 16; ++it) {
        u64 hd[2][3];
#pragma unroll
        for (int i = 0; i < 2; ++i)
#pragma unroll
            for (int w = 0; w < 3; ++w) {
                u64 m = e[i][w];
                u64 l = (w > 0) ? e[i][w - 1] : 0ull;
                u64 r = (w < 2) ? e[i][w + 1] : 0ull;
                hd[i][w] = m | (m << 1) | (m >> 1) | (l >> 63) | (r << 63);
            }
#pragma unroll
        for (int w = 0; w < 3; ++w) {
            u64 up = (u64)__shfl_up((long long)hd[1][w], 1);
            if (lane == 0) up = 0ull;
            u64 dn = (u64)__shfl_down((long long)hd[0][w], 1);
            if (lane == 63) dn = 0ull;
            e[0][w] |= k[0][w] & (up | hd[0][w] | hd[1][w]);
            e[1][w] |= k[1][w] & (hd[0][w] | hd[1][w] | dn);
        }
    }

    // store tile rows (region rows 16..79 -> lanes 8..39), mid word only
    if (lane >= 8 && lane < 40) {
#pragma unroll
        for (int i = 0; i < 2; ++i) {
            int gy = y0 - 16 + 2 * lane + i;
            u64 word = e[i][1];
            float* orow = out + (size_t)(b * HH + gy) * WW + x0;
            for (int c = 0; c < 64; c += 4) {
                float4 v;
                v.x = ((word >> c) & 1ull)       ? 1.f : 0.f;
                v.y = ((word >> (c + 1)) & 1ull) ? 1.f : 0.f;
                v.z = ((word >> (c + 2)) & 1ull) ? 1.f : 0.f;
                v.w = ((word >> (c + 3)) & 1ull) ? 1.f : 0.f;
                *reinterpret_cast<float4*>(orow + c) = v;
            }
        }
    }
}

extern "C" void kernel_launch(void* const* d_in, const int* in_sizes, int n_in,
                              void* d_out, int out_size, void* d_ws, size_t ws_size,
                              hipStream_t stream) {
    const float* in = (const float*)d_in[0];
    float* out = (float*)d_out;

    u64* strongB = (u64*)d_ws;                       // 1 MB
    u64* weakB   = strongB + (size_t)NB * HH * WPR;  // 1 MB

    canny_s1<<<dim3(NB * 16 * 16), 256, 0, stream>>>(in, strongB, weakB);
    canny_s2<<<dim3(NB * 16 * 16 / 4), 256, 0, stream>>>(strongB, weakB, out);
}

// Round 13
// 142.445 us; speedup vs baseline: 1.0503x; 1.0503x over previous
//
#include <hip/hip_runtime.h>
#include <math.h>
#include <stdint.h>

typedef unsigned long long u64;

#define HH 1024
#define WW 1024
#define NB 8
#define WPR 16  // u64 words per image row (1024/64)

// s1 tile: 64 wide x 32 tall. LDS (manual offsets, all 16B-aligned):
//   sInF  [38][72] f32 @ 0      (10944 B)  rows y0-3..y0+34, cols x0-3..x0+66 (+2 pad)
//   sBlF  [36][68] f32 @ 10944  ( 9792 B)  rows y0-2..y0+33, cols x0-2..x0+65
//   sBkt  [34][20]  u8 @ 20736  (  680 B)  2-bit buckets, 17 bytes used/row
//   sMagF [34][68] f32 = alias of sInF     rows y0-1..y0+32, cols x0-1..x0+64 (+2 pad)
#define SMEM_BYTES 21424

// Exact bucket: bit-identical to the validated reference chain (R9-R11 pass).
__device__ __forceinline__ int bucket_exact(float sy, float sx) {
#pragma clang fp contract(off)
    float ang = (float)atan2((double)sy, (double)sx);
    float deg = ang * 57.29577951308232f;  // f32(180/pi)
    if (deg < 0.f) deg += 180.f;
    if (deg < 22.5f || deg >= 157.5f) return 0;
    if (deg < 67.5f) return 1;
    if (deg < 112.5f) return 2;
    return 3;
}

// Guarded bucket (validated R10/R11): cheap tan-ratio away from boundaries,
// bit-exact atan2 chain within the guard band.
__device__ __forceinline__ int bucket_of(float sy, float sx) {
#pragma clang fp contract(off)
    const float t1 = 0.41421356237309503f;  // tan 22.5
    const float t2 = 2.414213562373095f;    // tan 67.5
    float ax = fabsf(sx), ay = fabsf(sy);
    float r1 = t1 * ax, r2 = t2 * ax;
    bool near1 = fabsf(ay - r1) <= 1e-4f * (ay + r1);
    bool near2 = fabsf(ay - r2) <= 1e-4f * (ay + r2);
    if (near1 | near2) return bucket_exact(sy, sx);
    if (ay < r1) return 0;
    if (ay < r2) return ((sx > 0.f) == (sy > 0.f)) ? 1 : 3;
    return 2;
}

// ---------------- Kernel 1: blur + sobel + NMS + double threshold -> bitmaps ----------------
__global__ __launch_bounds__(256, 7) void canny_s1(const float* __restrict__ in,
                                                   u64* __restrict__ strongB,
                                                   u64* __restrict__ weakB) {
#pragma clang fp contract(off)
    const int bx  = blockIdx.x;
    const int b   = bx >> 9;          // image index
    const int rem = bx & 511;
    const int y0  = (rem >> 4) << 5;  // 32 tile rows
    const int x0  = (rem & 15) << 6;  // 16 tile cols
    const float* img = in + (size_t)b * (HH * WW);

    __shared__ __align__(16) char smem[SMEM_BYTES];
    float* sInF = (float*)smem;                            // [38][72]
    float* sBlF = (float*)(smem + 10944);                  // [36][68]
    unsigned char* sBkt = (unsigned char*)(smem + 20736);  // [34][20]
    float* sMagF = sInF;                                   // [34][68] alias

    const int tid = threadIdx.x;

    // ---- Phase 0: load input tile, zero outside image ----
    for (int idx = tid; idx < 38 * 70; idx += 256) {
        int r = idx / 70, c = idx - r * 70;
        int gy = y0 - 3 + r, gx = x0 - 3 + c;
        float v = 0.f;
        if ((unsigned)gy < HH && (unsigned)gx < WW) v = img[gy * WW + gx];
        sInF[r * 72 + c] = v;
    }
    __syncthreads();

    // ---- Phase 1: Gaussian blur, 4 px/thread, b128 LDS reads ----
    for (int q = tid; q < 36 * 17; q += 256) {
        int r = q / 17, c4 = (q - r * 17) * 4;
        const float4* p0 = (const float4*)&sInF[r * 72 + c4];
        const float4* p1 = (const float4*)&sInF[(r + 1) * 72 + c4];
        const float4* p2 = (const float4*)&sInF[(r + 2) * 72 + c4];
        float4 a0 = p0[0], b0 = p0[1];
        float4 a1 = p1[0], b1 = p1[1];
        float4 a2 = p2[0], b2 = p2[1];
        float w0[6] = {a0.x, a0.y, a0.z, a0.w, b0.x, b0.y};
        float w1[6] = {a1.x, a1.y, a1.z, a1.w, b1.x, b1.y};
        float w2[6] = {a2.x, a2.y, a2.z, a2.w, b2.x, b2.y};
        int gy = y0 - 2 + r;
        float res[4];
#pragma unroll
        for (int j = 0; j < 4; ++j) {
            // exact reference row-major order per pixel
            float s = w0[j] * 0.0625f;
            s += w0[j + 1] * 0.125f;
            s += w0[j + 2] * 0.0625f;
            s += w1[j] * 0.125f;
            s += w1[j + 1] * 0.25f;
            s += w1[j + 2] * 0.125f;
            s += w2[j] * 0.0625f;
            s += w2[j + 1] * 0.125f;
            s += w2[j + 2] * 0.0625f;
            int gx = x0 - 2 + c4 + j;
            res[j] = ((unsigned)gy < HH && (unsigned)gx < WW) ? s : 0.f;
        }
        float4 outv;
        outv.x = res[0]; outv.y = res[1]; outv.z = res[2]; outv.w = res[3];
        *(float4*)&sBlF[r * 68 + c4] = outv;
    }
    __syncthreads();

    // ---- Phase 2: sobel + mag + bucket (2-bit packed), 4 px/thread ----
    // Quad c4=64 computes pad cols 66,67 from in-LDS garbage; pads never read.
    for (int q = tid; q < 34 * 17; q += 256) {
        int r = q / 17, c4 = (q - r * 17) * 4;
        const float4* p0 = (const float4*)&sBlF[r * 68 + c4];
        const float4* p1 = (const float4*)&sBlF[(r + 1) * 68 + c4];
        const float4* p2 = (const float4*)&sBlF[(r + 2) * 68 + c4];
        float4 a0 = p0[0], b0 = p0[1];
        float4 a1 = p1[0], b1 = p1[1];
        float4 a2 = p2[0], b2 = p2[1];
        float w0[6] = {a0.x, a0.y, a0.z, a0.w, b0.x, b0.y};
        float w1[6] = {a1.x, a1.y, a1.z, a1.w, b1.x, b1.y};
        float w2[6] = {a2.x, a2.y, a2.z, a2.w, b2.x, b2.y};
        int gy = y0 - 1 + r;
        float res[4];
        unsigned bpack = 0;
#pragma unroll
        for (int j = 0; j < 4; ++j) {
            // exact reference row-major signed order per pixel
            float gxv = -w0[j];
            gxv += w0[j + 2];
            gxv -= 2.f * w1[j];
            gxv += 2.f * w1[j + 2];
            gxv -= w2[j];
            gxv += w2[j + 2];
            float gyv = -w0[j];
            gyv -= 2.f * w0[j + 1];
            gyv -= w0[j + 2];
            gyv += w2[j];
            gyv += 2.f * w2[j + 1];
            gyv += w2[j + 2];
            float xx = gxv * gxv;
            float yy = gyv * gyv;
            float v = sqrtf(xx + yy);
            int gx = x0 - 1 + c4 + j;
            bool inb = ((unsigned)gy < HH && (unsigned)gx < WW);
            res[j] = inb ? v : 0.f;
            bpack |= (unsigned)bucket_of(gyv, gxv) << (2 * j);
        }
        float4 outv;
        outv.x = res[0]; outv.y = res[1]; outv.z = res[2]; outv.w = res[3];
        *(float4*)&sMagF[r * 68 + c4] = outv;
        sBkt[r * 20 + (c4 >> 2)] = (unsigned char)bpack;
    }
    __syncthreads();

    // ---- Phase 3: NMS + threshold, column-per-lane, 4 rows/step x 2 steps ----
    const int lane = tid & 63;
    const int wv   = tid >> 6;
    const int x    = lane;  // tile col

#pragma unroll
    for (int s = 0; s < 2; ++s) {
        int t0 = wv * 8 + s * 4;  // tile-row base; mag window rows t0..t0+5
        float mm[6][3];
#pragma unroll
        for (int rr = 0; rr < 6; ++rr)
#pragma unroll
            for (int cc = 0; cc < 3; ++cc)
                mm[rr][cc] = sMagF[(t0 + rr) * 68 + (x + cc)];

        bool st[4], wk[4];
#pragma unroll
        for (int j = 0; j < 4; ++j) {
            int mrow = t0 + 1 + j;
            int xb = x + 1;
            int bk = (sBkt[mrow * 20 + (xb >> 2)] >> ((xb & 3) * 2)) & 3;
            float m = mm[j + 1][1];
            float n1, n2;
            if (bk == 0)      { n1 = mm[j + 1][2]; n2 = mm[j + 1][0]; }
            else if (bk == 1) { n1 = mm[j][2];     n2 = mm[j + 2][0]; }
            else if (bk == 2) { n1 = mm[j][1];     n2 = mm[j + 2][1]; }
            else              { n1 = mm[j][0];     n2 = mm[j + 2][2]; }
            bool keep = (m >= n1) && (m >= n2);
            st[j] = keep && (m >= 0.3f);
            wk[j] = keep && (m >= 0.1f) && (m < 0.3f);
        }

        u64 bs0 = __ballot(st[0]), bs1 = __ballot(st[1]);
        u64 bs2 = __ballot(st[2]), bs3 = __ballot(st[3]);
        u64 bw0 = __ballot(wk[0]), bw1 = __ballot(wk[1]);
        u64 bw2 = __ballot(wk[2]), bw3 = __ballot(wk[3]);
        if (lane == 0) {
            size_t o = (size_t)(b * HH + y0 + t0) * WPR + (x0 >> 6);
            strongB[o]           = bs0;
            strongB[o + WPR]     = bs1;
            strongB[o + 2 * WPR] = bs2;
            strongB[o + 3 * WPR] = bs3;
            weakB[o]             = bw0;
            weakB[o + WPR]       = bw1;
            weakB[o + 2 * WPR]   = bw2;
            weakB[o + 3 * WPR]   = bw3;
        }
    }
}

// ---------------- Kernel 2: register+shfl bit-parallel hysteresis ----------------
// One wave per 64x64 tile; lane L holds region rows 2L,2L+1 (96 rows in 48
// lanes) x 3 u64 words in registers. Wave-synchronous Jacobi, no LDS.
__global__ __launch_bounds__(256) void canny_s2(const u64* __restrict__ strongB,
                                                const u64* __restrict__ weakB,
                                                float* __restrict__ out) {
    const int wave = threadIdx.x >> 6;
    const int lane = threadIdx.x & 63;
    const int tile = blockIdx.x * 4 + wave;  // 0..2047
    const int b   = tile >> 8;
    const int rem = tile & 255;
    const int y0  = (rem >> 4) << 6;
    const int x0  = (rem & 15) << 6;
    const int w0  = (x0 >> 6) - 1;

    u64 e[2][3], k[2][3];
#pragma unroll
    for (int i = 0; i < 2; ++i) {
        int rr = 2 * lane + i;
        int gy = y0 - 16 + rr;
#pragma unroll
        for (int w = 0; w < 3; ++w) {
            int gw = w0 + w;
            u64 s = 0, kk = 0;
            if (rr < 96 && (unsigned)gy < HH && (unsigned)gw < WPR) {
                size_t o = (size_t)(b * HH + gy) * WPR + gw;
                s  = strongB[o];
                kk = weakB[o];
            }
            e[i][w] = s;
            k[i][w] = kk;
        }
    }

    for (int it = 0; it < 16; ++it) {
        u64 hd[2][3];
#pragma unroll
        for (int i = 0; i < 2; ++i)
#pragma unroll
            for (int w = 0; w < 3; ++w) {
                u64 m = e[i][w];
                u64 l = (w > 0) ? e[i][w - 1] : 0ull;
                u64 r = (w < 2) ? e[i][w + 1] : 0ull;
                hd[i][w] = m | (m << 1) | (m >> 1) | (l >> 63) | (r << 63);
            }
#pragma unroll
        for (int w = 0; w < 3; ++w) {
            u64 up = (u64)__shfl_up((long long)hd[1][w], 1);
            if (lane == 0) up = 0ull;
            u64 dn = (u64)__shfl_down((long long)hd[0][w], 1);
            if (lane == 63) dn = 0ull;
            e[0][w] |= k[0][w] & (up | hd[0][w] | hd[1][w]);
            e[1][w] |= k[1][w] & (hd[0][w] | hd[1][w] | dn);
        }
    }

    // store tile rows (region rows 16..79 -> lanes 8..39), mid word only
    if (lane >= 8 && lane < 40) {
#pragma unroll
        for (int i = 0; i < 2; ++i) {
            int gy = y0 - 16 + 2 * lane + i;
            u64 word = e[i][1];
            float* orow = out + (size_t)(b * HH + gy) * WW + x0;
            for (int c = 0; c < 64; c += 4) {
                float4 v;
                v.x = ((word >> c) & 1ull)       ? 1.f : 0.f;
                v.y = ((word >> (c + 1)) & 1ull) ? 1.f : 0.f;
                v.z = ((word >> (c + 2)) & 1ull) ? 1.f : 0.f;
                v.w = ((word >> (c + 3)) & 1ull) ? 1.f : 0.f;
                *reinterpret_cast<float4*>(orow + c) = v;
            }
        }
    }
}

extern "C" void kernel_launch(void* const* d_in, const int* in_sizes, int n_in,
                              void* d_out, int out_size, void* d_ws, size_t ws_size,
                              hipStream_t stream) {
    const float* in = (const float*)d_in[0];
    float* out = (float*)d_out;

    u64* strongB = (u64*)d_ws;                       // 1 MB
    u64* weakB   = strongB + (size_t)NB * HH * WPR;  // 1 MB

    canny_s1<<<dim3(NB * 16 * 32), 256, 0, stream>>>(in, strongB, weakB);
    canny_s2<<<dim3(NB * 16 * 16 / 4), 256, 0, stream>>>(strongB, weakB, out);
}